// Round 1
// baseline (57117.242 us; speedup 1.0000x reference)
//
#include <hip/hip_runtime.h>
#include <math.h>

#define BATCH 512
#define SEQ_T 128
#define NIN   500
#define HID   1024
#define G3    3072   // 3*HID

// ---------------------------------------------------------------------------
// C[M,NN] = A[M,K] (row stride lda) @ W[NN,K]^T + bias[NN]
// 64x64 tile, 256 threads, 4x4 microtile, LDS staged with +4 pad (write-conflict free)
// ---------------------------------------------------------------------------
__global__ __launch_bounds__(256) void gemm_nt(
    const float* __restrict__ A, long lda,
    const float* __restrict__ W,
    const float* __restrict__ bias,
    float* __restrict__ C,
    int M, int NN, int K)
{
    __shared__ float As[16][68];
    __shared__ float Bs[16][68];
    const int tid = threadIdx.x;
    const int tx  = tid & 15;
    const int ty  = tid >> 4;
    const int bm  = blockIdx.x * 64;
    const int bn  = blockIdx.y * 64;
    const int lk  = tid & 15;   // k within tile (coalesced global reads)
    const int lr  = tid >> 4;   // row within tile, 4 passes of +16

    float acc[4][4] = {};

    for (int k0 = 0; k0 < K; k0 += 16) {
        #pragma unroll
        for (int i = 0; i < 4; i++) {
            int m  = lr + 16 * i;
            int gm = bm + m;
            int gn = bn + m;
            int gk = k0 + lk;
            float va = 0.f, vb = 0.f;
            if (gk < K) {
                if (gm < M)  va = A[(long)gm * lda + gk];
                if (gn < NN) vb = W[(long)gn * (long)K + gk];
            }
            As[lk][m] = va;
            Bs[lk][m] = vb;
        }
        __syncthreads();
        #pragma unroll
        for (int kk = 0; kk < 16; kk++) {
            float4 a4 = *(const float4*)&As[kk][ty * 4];
            float4 b4 = *(const float4*)&Bs[kk][tx * 4];
            float a[4] = {a4.x, a4.y, a4.z, a4.w};
            float b[4] = {b4.x, b4.y, b4.z, b4.w};
            #pragma unroll
            for (int i = 0; i < 4; i++)
                #pragma unroll
                for (int j = 0; j < 4; j++)
                    acc[i][j] = fmaf(a[i], b[j], acc[i][j]);
        }
        __syncthreads();
    }

    #pragma unroll
    for (int i = 0; i < 4; i++) {
        int gm = bm + ty * 4 + i;
        if (gm >= M) continue;
        #pragma unroll
        for (int j = 0; j < 4; j++) {
            int gn = bn + tx * 4 + j;
            if (gn >= NN) continue;
            C[(long)gm * NN + gn] = acc[i][j] + bias[gn];
        }
    }
}

// ---------------------------------------------------------------------------
// GRU elementwise update: r,z from summed projections; n uses r * (h-proj only)
// ---------------------------------------------------------------------------
__global__ __launch_bounds__(256) void gru_update(
    const float* __restrict__ gx,   // x@W_ih^T + b_ih   [B, 3H]
    const float* __restrict__ gh,   // h@W_hh^T + b_hh   [B, 3H]
    const float* __restrict__ hprev,
    float* __restrict__ hnew)
{
    int idx = blockIdx.x * 256 + threadIdx.x;
    if (idx >= BATCH * HID) return;
    int b  = idx >> 10;
    int hi = idx & (HID - 1);
    const float* gxr = gx + (long)b * G3;
    const float* ghr = gh + (long)b * G3;
    float xr = gxr[hi], xz = gxr[HID + hi], xn = gxr[2 * HID + hi];
    float hr = ghr[hi], hz = ghr[HID + hi], hn = ghr[2 * HID + hi];
    float r = 1.f / (1.f + expf(-(xr + hr)));
    float z = 1.f / (1.f + expf(-(xz + hz)));
    float n = tanhf(xn + r * hn);
    hnew[idx] = (1.f - z) * n + z * hprev[idx];
}

// ---------------------------------------------------------------------------
// block reductions (256 threads = 4 waves of 64)
// ---------------------------------------------------------------------------
__device__ __forceinline__ float block_reduce_sum(float v) {
    __shared__ float red[4];
    #pragma unroll
    for (int o = 32; o > 0; o >>= 1) v += __shfl_down(v, o);
    __syncthreads();
    if ((threadIdx.x & 63) == 0) red[threadIdx.x >> 6] = v;
    __syncthreads();
    return red[0] + red[1] + red[2] + red[3];
}

__device__ __forceinline__ float block_reduce_max(float v) {
    __shared__ float red[4];
    #pragma unroll
    for (int o = 32; o > 0; o >>= 1) v = fmaxf(v, __shfl_down(v, o));
    __syncthreads();
    if ((threadIdx.x & 63) == 0) red[threadIdx.x >> 6] = v;
    __syncthreads();
    return fmaxf(fmaxf(red[0], red[1]), fmaxf(red[2], red[3]));
}

// ---------------------------------------------------------------------------
// LayerNorm + SiLU, in-place on z [B, H]; one block (256 thr) per row
// ---------------------------------------------------------------------------
__global__ __launch_bounds__(256) void ln_silu(
    float* __restrict__ z,
    const float* __restrict__ gamma,
    const float* __restrict__ beta)
{
    int b = blockIdx.x;
    float* row = z + (long)b * HID;
    float v[4];
    float s = 0.f;
    #pragma unroll
    for (int i = 0; i < 4; i++) { v[i] = row[threadIdx.x + 256 * i]; s += v[i]; }
    float mean = block_reduce_sum(s) * (1.f / HID);
    float vs = 0.f;
    #pragma unroll
    for (int i = 0; i < 4; i++) { float d = v[i] - mean; vs += d * d; }
    float var = block_reduce_sum(vs) * (1.f / HID);
    float inv = 1.f / sqrtf(var + 1e-5f);
    #pragma unroll
    for (int i = 0; i < 4; i++) {
        int col = threadIdx.x + 256 * i;
        float zz = (v[i] - mean) * inv * gamma[col] + beta[col];
        row[col] = zz / (1.f + expf(-zz));   // SiLU
    }
}

// ---------------------------------------------------------------------------
// mask(<0 -> -inf) + softmax + clip[0,0.1] + 20-iter rebalance; block per row
// Each thread owns cols {tid, tid+256} of the 500-wide row, in registers.
// ---------------------------------------------------------------------------
__global__ __launch_bounds__(256) void head_softmax_rebalance(
    const float* __restrict__ scores,
    float* __restrict__ out)
{
    int b = blockIdx.x;
    const float* srow = scores + (long)b * NIN;
    int i0 = threadIdx.x;
    int i1 = threadIdx.x + 256;
    bool v1 = (i1 < NIN);

    float s0 = srow[i0];
    if (s0 < 0.f) s0 = -INFINITY;
    float s1 = v1 ? srow[i1] : -INFINITY;
    if (s1 < 0.f) s1 = -INFINITY;

    float m  = block_reduce_max(fmaxf(s0, s1));
    float e0 = expf(s0 - m);               // exp(-inf)=0 handles mask
    float e1 = v1 ? expf(s1 - m) : 0.f;
    float Z  = block_reduce_sum(e0 + e1);

    float w0 = fminf(fmaxf(e0 / Z, 0.f), 0.1f);
    float w1 = v1 ? fminf(fmaxf(e1 / Z, 0.f), 0.1f) : 0.f;

    for (int it = 0; it < 20; it++) {
        float total  = block_reduce_sum(w0 + w1);
        float excess = total - 1.f;
        bool active  = excess > 1e-6f;
        float sur0 = fmaxf(w0 - 0.1f, 0.f);
        float sur1 = fmaxf(w1 - 0.1f, 0.f);
        float totsur = block_reduce_sum(sur0 + sur1);
        float u0, u1;
        if (totsur > 0.f) {
            float k = excess / fmaxf(totsur, 1e-12f);
            u0 = w0 - sur0 * k;
            u1 = w1 - sur1 * k;
        } else {
            u0 = w0 - excess / (float)NIN;
            u1 = w1 - excess / (float)NIN;
        }
        u0 = fminf(fmaxf(u0, 0.f), 0.1f);
        u1 = fminf(fmaxf(u1, 0.f), 0.1f);
        if (active) { w0 = u0; w1 = u1; }
    }

    out[(long)b * NIN + i0] = w0;
    if (v1) out[(long)b * NIN + i1] = w1;
}

// ---------------------------------------------------------------------------
extern "C" void kernel_launch(void* const* d_in, const int* in_sizes, int n_in,
                              void* d_out, int out_size, void* d_ws, size_t ws_size,
                              hipStream_t stream)
{
    const float* x     = (const float*)d_in[0];
    const float* w_ih0 = (const float*)d_in[1];
    const float* w_hh0 = (const float*)d_in[2];
    const float* b_ih0 = (const float*)d_in[3];
    const float* b_hh0 = (const float*)d_in[4];
    const float* w_ih1 = (const float*)d_in[5];
    const float* w_hh1 = (const float*)d_in[6];
    const float* b_ih1 = (const float*)d_in[7];
    const float* b_hh1 = (const float*)d_in[8];
    const float* w1    = (const float*)d_in[9];
    const float* b1    = (const float*)d_in[10];
    const float* ln_g  = (const float*)d_in[11];
    const float* ln_b  = (const float*)d_in[12];
    const float* w2    = (const float*)d_in[13];
    const float* b2    = (const float*)d_in[14];
    float* out = (float*)d_out;

    float* ws  = (float*)d_ws;
    float* h0a = ws;  ws += (size_t)BATCH * HID;
    float* h0b = ws;  ws += (size_t)BATCH * HID;
    float* h1a = ws;  ws += (size_t)BATCH * HID;
    float* h1b = ws;  ws += (size_t)BATCH * HID;
    float* gx  = ws;  ws += (size_t)BATCH * G3;
    float* gh  = ws;  ws += (size_t)BATCH * G3;
    float* zb  = ws;  ws += (size_t)BATCH * HID;
    float* sc  = ws;  ws += (size_t)BATCH * NIN;

    hipMemsetAsync(h0a, 0, (size_t)BATCH * HID * sizeof(float), stream);
    hipMemsetAsync(h1a, 0, (size_t)BATCH * HID * sizeof(float), stream);

    dim3 blk(256);
    dim3 gGate(BATCH / 64, G3 / 64);                 // 8 x 48
    dim3 gUpd((BATCH * HID) / 256);                  // 2048

    float* h0p = h0a; float* h0n = h0b;
    float* h1p = h1a; float* h1n = h1b;

    for (int t = 0; t < SEQ_T; t++) {
        // layer 0
        gemm_nt<<<gGate, blk, 0, stream>>>(x + (long)t * NIN, (long)SEQ_T * NIN,
                                           w_ih0, b_ih0, gx, BATCH, G3, NIN);
        gemm_nt<<<gGate, blk, 0, stream>>>(h0p, HID, w_hh0, b_hh0, gh, BATCH, G3, HID);
        gru_update<<<gUpd, blk, 0, stream>>>(gx, gh, h0p, h0n);
        // layer 1 (consumes h0n = layer-0 output at step t)
        gemm_nt<<<gGate, blk, 0, stream>>>(h0n, HID, w_ih1, b_ih1, gx, BATCH, G3, HID);
        gemm_nt<<<gGate, blk, 0, stream>>>(h1p, HID, w_hh1, b_hh1, gh, BATCH, G3, HID);
        gru_update<<<gUpd, blk, 0, stream>>>(gx, gh, h1p, h1n);

        float* tmp;
        tmp = h0p; h0p = h0n; h0n = tmp;
        tmp = h1p; h1p = h1n; h1n = tmp;
    }

    // head: z = h_T @ w1^T + b1 ; LN + SiLU ; scores = z @ w2^T + b2
    dim3 gZ(BATCH / 64, HID / 64);                   // 8 x 16
    gemm_nt<<<gZ, blk, 0, stream>>>(h1p, HID, w1, b1, zb, BATCH, HID, HID);
    ln_silu<<<dim3(BATCH), blk, 0, stream>>>(zb, ln_g, ln_b);
    dim3 gS(BATCH / 64, (NIN + 63) / 64);            // 8 x 8
    gemm_nt<<<gS, blk, 0, stream>>>(zb, HID, w2, b2, sc, BATCH, NIN, HID);
    head_softmax_rebalance<<<dim3(BATCH), blk, 0, stream>>>(sc, out);
}